// Round 8
// baseline (52.071 us; speedup 1.0000x reference)
//
#include <hip/hip_runtime.h>
#include <math.h>

// Router: B=4, S=8192, D=1024, E=64, TOP_K=2 (all fp32)
// Output layout (fp32, concatenated flat):
//   [0,       65536)   top_k_probs   [4,8192,2]
//   [65536,   131072)  selected_experts (as float) [4,8192,2]
//   [131072,  2228224) router_logits [4,8192,64]
//
// R8 = R7's fp32-exact 3-level bf16-split MFMA with tiling restructured:
//  - 2 M-tiles per wave (128 tokens/block, grid 256 = 1 block/CU):
//    the 12 ds_read_b128/step now feed 48 MFMAs -> LDS-read traffic per
//    work HALVES (was the largest pipe, ~10us), W' DMA L2 traffic halves.
//  - W' LDS ring-of-3 (72 KB): DMA(t+2) issued at step t, consumed at
//    step t+2 -> 2 full compute steps of latency cover (R6/R7 gave the
//    DMA only its own step, which is why R7's counted vmcnt was null).
//  - counted waits: end-of-step queue = [DMA(t+1)x3, A(t+1)x4, DMA(t+2)x3]
//    -> vmcnt(7) retires exactly DMA(t+1) (vmcnt is in-order, m135).
// Numerics bitwise-identical to R6/R7 (same 6 terms, same K order).

typedef __attribute__((ext_vector_type(8))) short bf16x8;
typedef __attribute__((ext_vector_type(4))) float f32x4;

static constexpr int TOKENS = 32768;
static constexpr int DDIM   = 1024;
static constexpr int NEXP   = 64;
static constexpr size_t OFF_EXP = 65536;
static constexpr size_t OFF_LOG = 131072;

// ---- W 3-level split + fragment-order permute (validated R4-R7) ----
// element (e,k): tile n=e>>4, chunk c=k>>5, lane=(e&15)+16*((k&31)>>3), j=k&7
// dst (shorts) = ((c*4+n)*64 + lane)*8 + j
__global__ void w_split3_kernel(const float* __restrict__ w,
                                short* __restrict__ w1,
                                short* __restrict__ w2,
                                short* __restrict__ w3) {
    int idx = blockIdx.x * blockDim.x + threadIdx.x;
    for (int i = idx; i < NEXP * DDIM; i += gridDim.x * blockDim.x) {
        int e = i >> 10, k = i & 1023;
        float f = w[i];
        unsigned u1 = __float_as_uint(f);
        float f1 = __uint_as_float(u1 & 0xffff0000u);
        float r1 = f - f1;
        unsigned u2 = __float_as_uint(r1);
        float f2 = __uint_as_float(u2 & 0xffff0000u);
        float r2 = r1 - f2;
        unsigned u3 = __float_as_uint(r2);
        int n = e >> 4, c = k >> 5;
        int lane = (e & 15) + ((k & 31) >> 3) * 16;
        int j = k & 7;
        size_t dst = ((size_t)(c * 4 + n) * 64 + lane) * 8 + j;
        w1[dst] = (short)(u1 >> 16);
        w2[dst] = (short)(u2 >> 16);
        w3[dst] = (short)(u3 >> 16);
    }
}

__device__ inline void split8(float4 a, float4 b,
                              bf16x8& o1, bf16x8& o2, bf16x8& o3) {
    float f[8] = {a.x, a.y, a.z, a.w, b.x, b.y, b.z, b.w};
#pragma unroll
    for (int j = 0; j < 8; ++j) {
        unsigned u1 = __float_as_uint(f[j]);
        float f1 = __uint_as_float(u1 & 0xffff0000u);
        float r1 = f[j] - f1;
        unsigned u2 = __float_as_uint(r1);
        float f2 = __uint_as_float(u2 & 0xffff0000u);
        float r2 = r1 - f2;
        o1[j] = (short)(u1 >> 16);
        o2[j] = (short)(u2 >> 16);
        o3[j] = (short)(__float_as_uint(r2) >> 16);
    }
}

// global->LDS DMA, 16B/lane. LDS dest = wave-uniform base + lane*16 (HW);
// global src is per-lane.
typedef const __attribute__((address_space(1))) unsigned int* gas1_t;
typedef __attribute__((address_space(3))) unsigned int* las3_t;
__device__ inline void stage16(const void* g, void* l) {
    __builtin_amdgcn_global_load_lds((gas1_t)(uintptr_t)g,
                                     (las3_t)(uintptr_t)l, 16, 0, 0);
}

__global__ __launch_bounds__(512, 2)
void router_mfma_kernel(const float* __restrict__ h,
                        const short* __restrict__ w1,
                        const short* __restrict__ w2,
                        const short* __restrict__ w3,
                        float* __restrict__ out) {
    // ring of 3 staging bufs, 24 KB each: buf b at smem + b*24576.
    // Each buf: [khalf][arr][n] x 1KB segments (layout validated R6/R7).
    // Combine phase overlays smem+24576 (buf1: last DMA lands step 12,
    // last read step 13 -> no hazard with step-15 readers of buf0).
    __shared__ alignas(16) char smem[73728];
    const int tid   = threadIdx.x;
    const int lane  = tid & 63;
    const int wv    = tid >> 6;     // 0..7
    const int khalf = wv & 1;       // K half (0: k<512, 1: k>=512)
    const int mg    = wv >> 1;      // token group 0..3 (32 tokens each)
    const int token0 = blockIdx.x * 128 + mg * 32;   // tiles at +0, +16
    const int arow  = lane & 15;    // A-frag row (token within tile)
    const int ks    = lane >> 4;    // k slice within chunk

    const float* ap0 = h + (size_t)(token0 + arow) * DDIM + khalf * 512 + ks * 8;
    const float* ap1 = ap0 + (size_t)16 * DDIM;

    // staging assignment: seg = wv*3+i; seg = (a*4+n)*2 + kh
    const short* warr[3] = {w1, w2, w3};
    const char* gsrc[3];
    int ldso[3];
#pragma unroll
    for (int i = 0; i < 3; ++i) {
        int seg = wv * 3 + i;
        int kh = seg & 1;
        int an = seg >> 1;          // 0..11
        int a = an >> 2, n = an & 3;
        gsrc[i] = (const char*)warr[a] + (size_t)(kh * 64 + n) * 1024 + lane * 16;
        ldso[i] = (kh * 12 + a * 4 + n) * 1024;
    }

#define STAGE(bb, cc)                                                      \
    {                                                                      \
        _Pragma("unroll")                                                  \
        for (int i = 0; i < 3; ++i)                                        \
            stage16(gsrc[i] + (size_t)(cc) * 4096,                         \
                    smem + (bb) * 24576 + ldso[i]);                        \
    }

    f32x4 acc[2][4];
#pragma unroll
    for (int m = 0; m < 2; ++m)
#pragma unroll
        for (int n = 0; n < 4; ++n)
#pragma unroll
            for (int r = 0; r < 4; ++r) acc[m][n][r] = 0.0f;

    // A register ping-pong: [slot][tile][half]; all indices compile-time.
    float4 ringA[2][2][2];

    // prologue: A(0) x4, DMA(0) x3, DMA(1) x3 -> retire A(0)+DMA(0): vmcnt(3)
    ringA[0][0][0] = *reinterpret_cast<const float4*>(ap0);
    ringA[0][0][1] = *reinterpret_cast<const float4*>(ap0 + 4);
    ringA[0][1][0] = *reinterpret_cast<const float4*>(ap1);
    ringA[0][1][1] = *reinterpret_cast<const float4*>(ap1 + 4);
    STAGE(0, 0);
    STAGE(1, 1);
    asm volatile("s_waitcnt vmcnt(3)" ::: "memory");
    __builtin_amdgcn_s_barrier();

#pragma unroll
    for (int t = 0; t < 16; ++t) {
        const int slot  = t & 1;
        const int nslot = slot ^ 1;
        if (t + 1 < 16) {                       // A(t+1) x4 -> other slot
            ringA[nslot][0][0] =
                *reinterpret_cast<const float4*>(ap0 + (t + 1) * 32);
            ringA[nslot][0][1] =
                *reinterpret_cast<const float4*>(ap0 + (t + 1) * 32 + 4);
            ringA[nslot][1][0] =
                *reinterpret_cast<const float4*>(ap1 + (t + 1) * 32);
            ringA[nslot][1][1] =
                *reinterpret_cast<const float4*>(ap1 + (t + 1) * 32 + 4);
        }
        if (t + 2 < 16) STAGE((t + 2) % 3, t + 2);   // DMA(t+2) x3

        bf16x8 A1a, A2a, A3a, A1b, A2b, A3b;
        split8(ringA[slot][0][0], ringA[slot][0][1], A1a, A2a, A3a);
        split8(ringA[slot][1][0], ringA[slot][1][1], A1b, A2b, A3b);

        const char* wb = smem + (t % 3) * 24576 + khalf * 12288 + lane * 16;
#pragma unroll
        for (int n = 0; n < 4; ++n) {
            bf16x8 W1v = *reinterpret_cast<const bf16x8*>(wb + n * 1024);
            bf16x8 W2v = *reinterpret_cast<const bf16x8*>(wb + n * 1024 + 4096);
            bf16x8 W3v = *reinterpret_cast<const bf16x8*>(wb + n * 1024 + 8192);
            f32x4 t0 = acc[0][n];
            t0 = __builtin_amdgcn_mfma_f32_16x16x32_bf16(A3a, W1v, t0, 0, 0, 0);
            t0 = __builtin_amdgcn_mfma_f32_16x16x32_bf16(A1a, W3v, t0, 0, 0, 0);
            t0 = __builtin_amdgcn_mfma_f32_16x16x32_bf16(A2a, W2v, t0, 0, 0, 0);
            t0 = __builtin_amdgcn_mfma_f32_16x16x32_bf16(A2a, W1v, t0, 0, 0, 0);
            t0 = __builtin_amdgcn_mfma_f32_16x16x32_bf16(A1a, W2v, t0, 0, 0, 0);
            t0 = __builtin_amdgcn_mfma_f32_16x16x32_bf16(A1a, W1v, t0, 0, 0, 0);
            acc[0][n] = t0;
            f32x4 t1 = acc[1][n];
            t1 = __builtin_amdgcn_mfma_f32_16x16x32_bf16(A3b, W1v, t1, 0, 0, 0);
            t1 = __builtin_amdgcn_mfma_f32_16x16x32_bf16(A1b, W3v, t1, 0, 0, 0);
            t1 = __builtin_amdgcn_mfma_f32_16x16x32_bf16(A2b, W2v, t1, 0, 0, 0);
            t1 = __builtin_amdgcn_mfma_f32_16x16x32_bf16(A2b, W1v, t1, 0, 0, 0);
            t1 = __builtin_amdgcn_mfma_f32_16x16x32_bf16(A1b, W2v, t1, 0, 0, 0);
            t1 = __builtin_amdgcn_mfma_f32_16x16x32_bf16(A1b, W1v, t1, 0, 0, 0);
            acc[1][n] = t1;
        }

        if (t <= 13) {
            // outstanding: DMA(t+1)x3, A(t+1)x4, DMA(t+2)x3 -> retire DMA(t+1)
            asm volatile("s_waitcnt vmcnt(7)" ::: "memory");
            __builtin_amdgcn_s_barrier();
        } else if (t == 14) {
            // outstanding: DMA(15)x3, A(15)x4 -> retire DMA(15)
            asm volatile("s_waitcnt vmcnt(4)" ::: "memory");
            __builtin_amdgcn_s_barrier();
        }
    }

    // ---- combine K-halves via LDS overlay at smem+24576 ----
    if (khalf == 1) {
        float* cb = (float*)(smem + 24576) + (size_t)(mg * 64 + lane) * 33;
#pragma unroll
        for (int m = 0; m < 2; ++m)
#pragma unroll
            for (int n = 0; n < 4; ++n)
#pragma unroll
                for (int r = 0; r < 4; ++r)
                    cb[m * 16 + n * 4 + r] = acc[m][n][r];
    }
    __syncthreads();
    if (khalf != 0) return;

    {
        const float* cb = (const float*)(smem + 24576)
                        + (size_t)(mg * 64 + lane) * 33;
#pragma unroll
        for (int m = 0; m < 2; ++m)
#pragma unroll
            for (int n = 0; n < 4; ++n)
#pragma unroll
                for (int r = 0; r < 4; ++r)
                    acc[m][n][r] += cb[m * 16 + n * 4 + r];
    }

    const int rbase = (lane >> 4) * 4;   // C/D row group (token offset)
    const int col   = lane & 15;         // C/D col (expert within tile)

    // ---- logits ----
#pragma unroll
    for (int m = 0; m < 2; ++m)
#pragma unroll
        for (int n = 0; n < 4; ++n)
#pragma unroll
            for (int r = 0; r < 4; ++r)
                out[OFF_LOG + (size_t)(token0 + m * 16 + rbase + r) * NEXP
                    + n * 16 + col] = acc[m][n][r];

    // ---- softmax + top-2 per token (16-lane groups, xor 1,2,4,8) ----
#pragma unroll
    for (int m = 0; m < 2; ++m)
#pragma unroll
    for (int r = 0; r < 4; ++r) {
        const int token = token0 + m * 16 + rbase + r;
        float mx = fmaxf(fmaxf(acc[m][0][r], acc[m][1][r]),
                         fmaxf(acc[m][2][r], acc[m][3][r]));
#pragma unroll
        for (int d = 1; d <= 8; d <<= 1) mx = fmaxf(mx, __shfl_xor(mx, d, 64));

        float p[4];
        float s = 0.0f;
#pragma unroll
        for (int n = 0; n < 4; ++n) { p[n] = expf(acc[m][n][r] - mx); s += p[n]; }
#pragma unroll
        for (int d = 1; d <= 8; d <<= 1) s += __shfl_xor(s, d, 64);

        // local top-2 over n (expert = n*16 + col, ascending; '>' keeps lower)
        float v1 = -INFINITY, v2 = -INFINITY;
        int   i1 = NEXP,      i2 = NEXP;
#pragma unroll
        for (int n = 0; n < 4; ++n) {
            float v = p[n];
            int   ei = n * 16 + col;
            if (v > v1)      { v2 = v1; i2 = i1; v1 = v; i1 = ei; }
            else if (v > v2) { v2 = v;  i2 = ei; }
        }

        // merge across the 16 lanes of the group
#pragma unroll
        for (int d = 1; d <= 8; d <<= 1) {
            float ov1 = __shfl_xor(v1, d, 64);
            float ov2 = __shfl_xor(v2, d, 64);
            int   oi1 = __shfl_xor(i1, d, 64);
            int   oi2 = __shfl_xor(i2, d, 64);
            bool ofirst = (ov1 > v1) || (ov1 == v1 && oi1 < i1);
            float n1, n2; int ni1, ni2;
            if (ofirst) {
                n1 = ov1; ni1 = oi1;
                bool sec = (v1 > ov2) || (v1 == ov2 && i1 < oi2);
                n2 = sec ? v1 : ov2; ni2 = sec ? i1 : oi2;
            } else {
                n1 = v1; ni1 = i1;
                bool sec = (ov1 > v2) || (ov1 == v2 && oi1 < i2);
                n2 = sec ? ov1 : v2; ni2 = sec ? oi1 : i2;
            }
            v1 = n1; i1 = ni1; v2 = n2; i2 = ni2;
        }

        if (col == 0) {
            float t1 = v1 / s;
            float t2 = v2 / s;
            float dn = t1 + t2 + 1e-8f;
            float2 pr; pr.x = t1 / dn; pr.y = t2 / dn;
            *reinterpret_cast<float2*>(out + (size_t)token * 2) = pr;
            float2 ex; ex.x = (float)i1; ex.y = (float)i2;
            *reinterpret_cast<float2*>(out + OFF_EXP + (size_t)token * 2) = ex;
        }
    }
#undef STAGE
}

extern "C" void kernel_launch(void* const* d_in, const int* in_sizes, int n_in,
                              void* d_out, int out_size, void* d_ws, size_t ws_size,
                              hipStream_t stream) {
    const float* h = (const float*)d_in[0];
    const float* w = (const float*)d_in[1];
    float* out = (float*)d_out;
    // d_ws: W1 | W2 | W3, each 65536 shorts = 384 KiB total
    short* w1 = (short*)d_ws;
    short* w2 = w1 + (size_t)NEXP * DDIM;
    short* w3 = w2 + (size_t)NEXP * DDIM;
    hipLaunchKernelGGL(w_split3_kernel, dim3(128), dim3(256), 0, stream, w, w1, w2, w3);
    hipLaunchKernelGGL(router_mfma_kernel, dim3(TOKENS / 128), dim3(512), 0, stream,
                       h, w1, w2, w3, out);
}

// Round 9
// 43.682 us; speedup vs baseline: 1.1921x; 1.1921x over previous
//
#include <hip/hip_runtime.h>
#include <math.h>

// Router: B=4, S=8192, D=1024, E=64, TOP_K=2 (all fp32)
// Output layout (fp32, concatenated flat):
//   [0,       65536)   top_k_probs   [4,8192,2]
//   [65536,   131072)  selected_experts (as float) [4,8192,2]
//   [131072,  2228224) router_logits [4,8192,64]
//
// R9 = R7 (fp32-exact 3-level bf16-split MFMA, 64 tok/block, 512 thr,
// grid 512, 2 blocks/CU, 4 waves/SIMD — best-known structure, 43.6us)
// + W' LDS ring-of-3: DMA(t+2) issued at step t, consumed at step t+2
//   -> 2 full compute steps of latency slack. In R6/R7 DMA(t+1) was
//   issued at t with deadline end-of-t (~1 step) — the untested stall.
// End-of-step queue: [DMA(t+1)x3, A(t+1)x2, DMA(t+2)x3, A(t+2)x2]
//   -> vmcnt(7) retires exactly DMA(t+1). t=14 -> vmcnt(2).
// STAGE at t writes buf (t+2)%3=(t-1)%3 whose readers passed the
// end-of-(t-1) barrier. Combine overlays buf1 (last read t=13).
// Numerics bitwise-identical to R5-R8.

typedef __attribute__((ext_vector_type(8))) short bf16x8;
typedef __attribute__((ext_vector_type(4))) float f32x4;

static constexpr int TOKENS = 32768;
static constexpr int DDIM   = 1024;
static constexpr int NEXP   = 64;
static constexpr size_t OFF_EXP = 65536;
static constexpr size_t OFF_LOG = 131072;

// ---- W 3-level split + fragment-order permute (validated R4-R8) ----
__global__ void w_split3_kernel(const float* __restrict__ w,
                                short* __restrict__ w1,
                                short* __restrict__ w2,
                                short* __restrict__ w3) {
    int idx = blockIdx.x * blockDim.x + threadIdx.x;
    for (int i = idx; i < NEXP * DDIM; i += gridDim.x * blockDim.x) {
        int e = i >> 10, k = i & 1023;
        float f = w[i];
        unsigned u1 = __float_as_uint(f);
        float f1 = __uint_as_float(u1 & 0xffff0000u);
        float r1 = f - f1;
        unsigned u2 = __float_as_uint(r1);
        float f2 = __uint_as_float(u2 & 0xffff0000u);
        float r2 = r1 - f2;
        unsigned u3 = __float_as_uint(r2);
        int n = e >> 4, c = k >> 5;
        int lane = (e & 15) + ((k & 31) >> 3) * 16;
        int j = k & 7;
        size_t dst = ((size_t)(c * 4 + n) * 64 + lane) * 8 + j;
        w1[dst] = (short)(u1 >> 16);
        w2[dst] = (short)(u2 >> 16);
        w3[dst] = (short)(u3 >> 16);
    }
}

__device__ inline void split8(float4 a, float4 b,
                              bf16x8& o1, bf16x8& o2, bf16x8& o3) {
    float f[8] = {a.x, a.y, a.z, a.w, b.x, b.y, b.z, b.w};
#pragma unroll
    for (int j = 0; j < 8; ++j) {
        unsigned u1 = __float_as_uint(f[j]);
        float f1 = __uint_as_float(u1 & 0xffff0000u);
        float r1 = f[j] - f1;
        unsigned u2 = __float_as_uint(r1);
        float f2 = __uint_as_float(u2 & 0xffff0000u);
        float r2 = r1 - f2;
        o1[j] = (short)(u1 >> 16);
        o2[j] = (short)(u2 >> 16);
        o3[j] = (short)(__float_as_uint(r2) >> 16);
    }
}

typedef const __attribute__((address_space(1))) unsigned int* gas1_t;
typedef __attribute__((address_space(3))) unsigned int* las3_t;
__device__ inline void stage16(const void* g, void* l) {
    __builtin_amdgcn_global_load_lds((gas1_t)(uintptr_t)g,
                                     (las3_t)(uintptr_t)l, 16, 0, 0);
}

__global__ __launch_bounds__(512, 4)
void router_mfma_kernel(const float* __restrict__ h,
                        const short* __restrict__ w1,
                        const short* __restrict__ w2,
                        const short* __restrict__ w3,
                        float* __restrict__ out) {
    // ring of 3 staging bufs, 24 KB each, buf b at smem + b*24576.
    // Each buf: [khalf][arr][n] x 1KB segments (layout validated R6-R8).
    __shared__ alignas(16) char smem[73728];
    const int tid   = threadIdx.x;
    const int lane  = tid & 63;
    const int wv    = tid >> 6;     // 0..7
    const int khalf = wv & 1;       // K half (0: k<512, 1: k>=512)
    const int mg    = wv >> 1;      // M-tile group 0..3
    const int token0 = blockIdx.x * 64 + mg * 16;
    const int arow  = lane & 15;    // A-frag row (token within tile)
    const int ks    = lane >> 4;    // k slice within chunk

    const float* ap = h + (size_t)(token0 + arow) * DDIM + khalf * 512 + ks * 8;

    // staging assignment: seg = wv*3+i; seg = (a*4+n)*2 + kh
    const short* warr[3] = {w1, w2, w3};
    const char* gsrc[3];
    int ldso[3];
#pragma unroll
    for (int i = 0; i < 3; ++i) {
        int seg = wv * 3 + i;
        int kh = seg & 1;
        int an = seg >> 1;          // 0..11
        int a = an >> 2, n = an & 3;
        gsrc[i] = (const char*)warr[a] + (size_t)(kh * 64 + n) * 1024 + lane * 16;
        ldso[i] = (kh * 12 + a * 4 + n) * 1024;
    }

#define STAGE(bb, cc)                                                      \
    {                                                                      \
        _Pragma("unroll")                                                  \
        for (int i = 0; i < 3; ++i)                                        \
            stage16(gsrc[i] + (size_t)(cc) * 4096,                         \
                    smem + (bb) * 24576 + ldso[i]);                        \
    }

    f32x4 acc[4];
#pragma unroll
    for (int n = 0; n < 4; ++n)
#pragma unroll
        for (int r = 0; r < 4; ++r) acc[n][r] = 0.0f;

    // A-chunk register ring, depth 3; all indices compile-time (full unroll).
    float4 ring[3][2];

    // prologue: [DMA(0)x3, DMA(1)x3, A(0)x2, A(1)x2] -> retire DMA(0): vmcnt(7)
    STAGE(0, 0);
    STAGE(1, 1);
    ring[0][0] = *reinterpret_cast<const float4*>(ap);
    ring[0][1] = *reinterpret_cast<const float4*>(ap + 4);
    ring[1][0] = *reinterpret_cast<const float4*>(ap + 32);
    ring[1][1] = *reinterpret_cast<const float4*>(ap + 36);
    asm volatile("s_waitcnt vmcnt(7)" ::: "memory");
    __builtin_amdgcn_s_barrier();

#pragma unroll
    for (int t = 0; t < 16; ++t) {
        if (t + 2 < 16) {
            STAGE((t + 2) % 3, t + 2);             // DMA(t+2) -> buf (t-1)%3
            ring[(t + 2) % 3][0] =
                *reinterpret_cast<const float4*>(ap + (t + 2) * 32);
            ring[(t + 2) % 3][1] =
                *reinterpret_cast<const float4*>(ap + (t + 2) * 32 + 4);
        }

        bf16x8 A1f, A2f, A3f;
        split8(ring[t % 3][0], ring[t % 3][1], A1f, A2f, A3f);

        const char* wb = smem + (t % 3) * 24576 + khalf * 12288 + lane * 16;
#pragma unroll
        for (int n = 0; n < 4; ++n) {
            bf16x8 W1v = *reinterpret_cast<const bf16x8*>(wb + n * 1024);
            bf16x8 W2v = *reinterpret_cast<const bf16x8*>(wb + n * 1024 + 4096);
            bf16x8 W3v = *reinterpret_cast<const bf16x8*>(wb + n * 1024 + 8192);
            f32x4 t2 = acc[n];
            t2 = __builtin_amdgcn_mfma_f32_16x16x32_bf16(A3f, W1v, t2, 0, 0, 0);
            t2 = __builtin_amdgcn_mfma_f32_16x16x32_bf16(A1f, W3v, t2, 0, 0, 0);
            t2 = __builtin_amdgcn_mfma_f32_16x16x32_bf16(A2f, W2v, t2, 0, 0, 0);
            t2 = __builtin_amdgcn_mfma_f32_16x16x32_bf16(A2f, W1v, t2, 0, 0, 0);
            t2 = __builtin_amdgcn_mfma_f32_16x16x32_bf16(A1f, W2v, t2, 0, 0, 0);
            t2 = __builtin_amdgcn_mfma_f32_16x16x32_bf16(A1f, W1v, t2, 0, 0, 0);
            acc[n] = t2;
        }

        if (t <= 13) {
            // queue: [DMA(t+1)x3, A(t+1)x2, DMA(t+2)x3, A(t+2)x2]
            // -> vmcnt(7) retires exactly DMA(t+1)
            asm volatile("s_waitcnt vmcnt(7)" ::: "memory");
            __builtin_amdgcn_s_barrier();
        } else if (t == 14) {
            // queue: [DMA(15)x3, A(15)x2] -> retire DMA(15)
            asm volatile("s_waitcnt vmcnt(2)" ::: "memory");
            __builtin_amdgcn_s_barrier();
        }
    }

    // ---- combine K-halves via LDS overlay at buf1 (last read t=13) ----
    if (khalf == 1) {
        float* c = (float*)(smem + 24576) + (size_t)(mg * 64 + lane) * 17;
#pragma unroll
        for (int n = 0; n < 4; ++n)
#pragma unroll
            for (int r = 0; r < 4; ++r) c[n * 4 + r] = acc[n][r];
    }
    __syncthreads();
    if (khalf != 0) return;

    {
        const float* c = (const float*)(smem + 24576)
                       + (size_t)(mg * 64 + lane) * 17;
#pragma unroll
        for (int n = 0; n < 4; ++n)
#pragma unroll
            for (int r = 0; r < 4; ++r) acc[n][r] += c[n * 4 + r];
    }

    const int rbase = (lane >> 4) * 4;   // C/D row group (token offset)
    const int col   = lane & 15;         // C/D col (expert within tile)

    // ---- logits ----
#pragma unroll
    for (int n = 0; n < 4; ++n)
#pragma unroll
        for (int r = 0; r < 4; ++r)
            out[OFF_LOG + (size_t)(token0 + rbase + r) * NEXP + n * 16 + col]
                = acc[n][r];

    // ---- softmax + top-2 per token (16-lane groups, xor 1,2,4,8) ----
#pragma unroll
    for (int r = 0; r < 4; ++r) {
        const int token = token0 + rbase + r;
        float mx = fmaxf(fmaxf(acc[0][r], acc[1][r]),
                         fmaxf(acc[2][r], acc[3][r]));
#pragma unroll
        for (int d = 1; d <= 8; d <<= 1) mx = fmaxf(mx, __shfl_xor(mx, d, 64));

        float p[4];
        float s = 0.0f;
#pragma unroll
        for (int n = 0; n < 4; ++n) { p[n] = expf(acc[n][r] - mx); s += p[n]; }
#pragma unroll
        for (int d = 1; d <= 8; d <<= 1) s += __shfl_xor(s, d, 64);

        // local top-2 over n (expert = n*16 + col, ascending; '>' keeps lower)
        float v1 = -INFINITY, v2 = -INFINITY;
        int   i1 = NEXP,      i2 = NEXP;
#pragma unroll
        for (int n = 0; n < 4; ++n) {
            float v = p[n];
            int   ei = n * 16 + col;
            if (v > v1)      { v2 = v1; i2 = i1; v1 = v; i1 = ei; }
            else if (v > v2) { v2 = v;  i2 = ei; }
        }

        // merge across the 16 lanes of the group
#pragma unroll
        for (int d = 1; d <= 8; d <<= 1) {
            float ov1 = __shfl_xor(v1, d, 64);
            float ov2 = __shfl_xor(v2, d, 64);
            int   oi1 = __shfl_xor(i1, d, 64);
            int   oi2 = __shfl_xor(i2, d, 64);
            bool ofirst = (ov1 > v1) || (ov1 == v1 && oi1 < i1);
            float n1, n2; int ni1, ni2;
            if (ofirst) {
                n1 = ov1; ni1 = oi1;
                bool sec = (v1 > ov2) || (v1 == ov2 && i1 < oi2);
                n2 = sec ? v1 : ov2; ni2 = sec ? i1 : oi2;
            } else {
                n1 = v1; ni1 = i1;
                bool sec = (ov1 > v2) || (ov1 == v2 && oi1 < i2);
                n2 = sec ? ov1 : v2; ni2 = sec ? oi1 : i2;
            }
            v1 = n1; i1 = ni1; v2 = n2; i2 = ni2;
        }

        if (col == 0) {
            float t1 = v1 / s;
            float t2 = v2 / s;
            float dn = t1 + t2 + 1e-8f;
            float2 pr; pr.x = t1 / dn; pr.y = t2 / dn;
            *reinterpret_cast<float2*>(out + (size_t)token * 2) = pr;
            float2 ex; ex.x = (float)i1; ex.y = (float)i2;
            *reinterpret_cast<float2*>(out + OFF_EXP + (size_t)token * 2) = ex;
        }
    }
#undef STAGE
}

extern "C" void kernel_launch(void* const* d_in, const int* in_sizes, int n_in,
                              void* d_out, int out_size, void* d_ws, size_t ws_size,
                              hipStream_t stream) {
    const float* h = (const float*)d_in[0];
    const float* w = (const float*)d_in[1];
    float* out = (float*)d_out;
    // d_ws: W1 | W2 | W3, each 65536 shorts = 384 KiB total
    short* w1 = (short*)d_ws;
    short* w2 = w1 + (size_t)NEXP * DDIM;
    short* w3 = w2 + (size_t)NEXP * DDIM;
    hipLaunchKernelGGL(w_split3_kernel, dim3(128), dim3(256), 0, stream, w, w1, w2, w3);
    hipLaunchKernelGGL(router_mfma_kernel, dim3(TOKENS / 64), dim3(512), 0, stream,
                       h, w1, w2, w3, out);
}